// Round 1
// baseline (9928.984 us; speedup 1.0000x reference)
//
#include <hip/hip_runtime.h>
#include <stdint.h>

// T=1024, B=32, D=H=1024.  M = T*B = 32768.
typedef float  f32x4  __attribute__((ext_vector_type(4)));
typedef short  bf16x8 __attribute__((ext_vector_type(8)));

__device__ __forceinline__ unsigned short f2bf(float f) {
  union { float f; unsigned u; } v; v.f = f;
  unsigned r = v.u + 0x7fffu + ((v.u >> 16) & 1u);   // RNE, inputs are finite
  return (unsigned short)(r >> 16);
}
__device__ __forceinline__ float bf2f(unsigned short s) {
  union { unsigned u; float f; } v; v.u = ((unsigned)s) << 16; return v.f;
}
__device__ __forceinline__ bf16x8 pack8(float4 a, float4 b) {
  bf16x8 v;
  v[0]=(short)f2bf(a.x); v[1]=(short)f2bf(a.y); v[2]=(short)f2bf(a.z); v[3]=(short)f2bf(a.w);
  v[4]=(short)f2bf(b.x); v[5]=(short)f2bf(b.y); v[6]=(short)f2bf(b.z); v[7]=(short)f2bf(b.w);
  return v;
}
__device__ __forceinline__ f32x4 mfma16(bf16x8 a, bf16x8 b, f32x4 c) {
  return __builtin_amdgcn_mfma_f32_16x16x32_bf16(a, b, c, 0, 0, 0);
}

// ---------------------------------------------------------------------------
// Phase 1: wx = x @ Wx^T + bias  -> d_out (fp32, consumed in-place by phase 2)
//          delta = sigmoid(x @ Wd^T + b_delta) -> ws (bf16)
// NT-GEMM, 128x128 tile, BK=32, 4 waves (2x2 of 64x64), bf16 MFMA 16x16x32.
// LDS row stride 40 halves (80 B): 16-lane frag reads land on 8 distinct bank
// groups -> 2-way aliasing only (free).
// grid = (M/128=256, 16); blockIdx.y 0..7 -> Wx, 8..15 -> W_delta.
// ---------------------------------------------------------------------------
__global__ __launch_bounds__(256) void proj_kernel(
    const float* __restrict__ x,  const float* __restrict__ Wx,
    const float* __restrict__ Wd, const float* __restrict__ bias,
    const float* __restrict__ bd, float* __restrict__ wx_out,
    unsigned short* __restrict__ delta_out)
{
  __shared__ __align__(16) unsigned short lA[128 * 40];
  __shared__ __align__(16) unsigned short lB[128 * 40];

  const int tid  = threadIdx.x;
  const int lane = tid & 63;
  const int wv   = tid >> 6;
  const int wm   = (wv >> 1) * 64;
  const int wn   = (wv & 1) * 64;
  const int l15  = lane & 15, lhi = lane >> 4;

  const int  bm    = blockIdx.x;
  const int  bn    = blockIdx.y;
  const bool isd   = bn >= 8;
  const float* W   = isd ? Wd : Wx;
  const int  ncol0 = (bn & 7) * 128;
  const int  row0  = bm * 128;

  const int srow = tid >> 1;          // 0..127
  const int scol = (tid & 1) * 16;    // 0 or 16

  f32x4 acc[4][4] = {};

  for (int k0 = 0; k0 < 1024; k0 += 32) {
    const float* pa = x + (size_t)(row0 + srow) * 1024 + (k0 + scol);
    const float* pb = W + (size_t)(ncol0 + srow) * 1024 + (k0 + scol);
    float4 a0 = *(const float4*)(pa + 0), a1 = *(const float4*)(pa + 4);
    float4 a2 = *(const float4*)(pa + 8), a3 = *(const float4*)(pa + 12);
    float4 b0 = *(const float4*)(pb + 0), b1 = *(const float4*)(pb + 4);
    float4 b2 = *(const float4*)(pb + 8), b3 = *(const float4*)(pb + 12);

    *(bf16x8*)&lA[srow * 40 + scol]     = pack8(a0, a1);
    *(bf16x8*)&lA[srow * 40 + scol + 8] = pack8(a2, a3);
    *(bf16x8*)&lB[srow * 40 + scol]     = pack8(b0, b1);
    *(bf16x8*)&lB[srow * 40 + scol + 8] = pack8(b2, b3);
    __syncthreads();

    bf16x8 af[4], bfr[4];
    #pragma unroll
    for (int i = 0; i < 4; ++i) {
      af[i]  = *(const bf16x8*)&lA[(wm + i * 16 + l15) * 40 + lhi * 8];
      bfr[i] = *(const bf16x8*)&lB[(wn + i * 16 + l15) * 40 + lhi * 8];
    }
    #pragma unroll
    for (int i = 0; i < 4; ++i)
      #pragma unroll
      for (int j = 0; j < 4; ++j)
        acc[i][j] = mfma16(af[i], bfr[j], acc[i][j]);
    __syncthreads();
  }

  // C/D layout (verified, guide §3): col = lane&15, row = (lane>>4)*4 + reg
  #pragma unroll
  for (int i = 0; i < 4; ++i) {
    const int rbase = row0 + wm + i * 16 + lhi * 4;
    #pragma unroll
    for (int j = 0; j < 4; ++j) {
      const int col = ncol0 + wn + j * 16 + l15;
      #pragma unroll
      for (int r = 0; r < 4; ++r) {
        const size_t idx = (size_t)(rbase + r) * 1024 + col;
        const float v = acc[i][j][r];
        if (!isd) {
          wx_out[idx] = v + bias[col];
        } else {
          const float s = 1.0f / (1.0f + expf(-(v + bd[col])));
          delta_out[idx] = f2bf(s);
        }
      }
    }
  }
}

// ---------------------------------------------------------------------------
// Phase 2: persistent recurrence.
// grid = 16 WGs x 256 thr: blockIdx = bg*8 + chunk.
//   bg    in {0,1}: batch group of 16 (independent chains, own counter)
//   chunk in 0..7 : 128 output columns; wave wv owns 32 columns.
// R chunk lives in registers as MFMA B-fragments: rb[2][32] = 256 VGPR.
// h exchange: global bf16 hbuf, double-buffered by t parity. Publish ->
// __threadfence (agent release) -> atomicAdd(counter); consumer spins then
// acquire-fences, loads A-fragments directly global->VGPR (dwordx4 each).
// ---------------------------------------------------------------------------
__global__ __launch_bounds__(256, 1) void rnn_kernel(
    const float* __restrict__ R, const float* __restrict__ h0,
    float* __restrict__ out, const unsigned short* __restrict__ delta,
    unsigned short* __restrict__ hbuf, unsigned int* __restrict__ counters)
{
  const int tid  = threadIdx.x;
  const int lane = tid & 63;
  const int wv   = tid >> 6;
  const int l15  = lane & 15, lhi = lane >> 4;
  const int chunk = blockIdx.x & 7;
  const int bg    = blockIdx.x >> 3;
  const int B0    = bg * 16;
  const int cb    = chunk * 128 + wv * 32;
  unsigned int* cnt = counters + bg * 16;   // 64 B apart

  // Preload R fragments (B-operand layout: col = l&15, k = (l>>4)*8 + j)
  bf16x8 rb[2][32];
  #pragma unroll
  for (int nt = 0; nt < 2; ++nt) {
    const float* rrow = R + (size_t)(cb + nt * 16 + l15) * 1024 + lhi * 8;
    #pragma unroll
    for (int kt = 0; kt < 32; ++kt) {
      float4 u0 = *(const float4*)(rrow + kt * 32);
      float4 u1 = *(const float4*)(rrow + kt * 32 + 4);
      rb[nt][kt] = pack8(u0, u1);
    }
  }

  // Local fp32 h for the 16 (b,j) pairs this lane owns (C-frag layout).
  float hloc[2][4];
  #pragma unroll
  for (int nt = 0; nt < 2; ++nt)
    #pragma unroll
    for (int r = 0; r < 4; ++r) {
      const int b = B0 + lhi * 4 + r;
      const int j = cb + nt * 16 + l15;
      const float v = h0[(size_t)b * 1024 + j];
      hloc[nt][r] = v;
      hbuf[(size_t)b * 1024 + j] = f2bf(v);   // publish h_init into buffer 0
    }
  __syncthreads();
  if (tid == 0) { __threadfence(); atomicAdd(cnt, 1u); }

  unsigned int target = 8;
  const int abase = (B0 + l15) * 1024 + lhi * 8;   // A-frag base (halves)

  for (int t = 0; t < 1024; ++t) {
    const unsigned short* hin  = hbuf + (t & 1) * 32768;
    unsigned short*       hout = hbuf + ((t & 1) ^ 1) * 32768;
    float*                outp = out + (size_t)t * 32768;
    const unsigned short* dp   = delta + (size_t)t * 32768;

    // Prefetch this step's wx / delta (independent of the h publishes).
    float wxv[2][4], dv[2][4];
    #pragma unroll
    for (int nt = 0; nt < 2; ++nt)
      #pragma unroll
      for (int r = 0; r < 4; ++r) {
        const size_t idx = (size_t)(B0 + lhi * 4 + r) * 1024 + (cb + nt * 16 + l15);
        wxv[nt][r] = outp[idx];
        dv[nt][r]  = bf2f(dp[idx]);
      }

    // Wait until all 8 chunks of h_{t-1} for this batch group are published.
    if (tid == 0) {
      while (__hip_atomic_load(cnt, __ATOMIC_RELAXED, __HIP_MEMORY_SCOPE_AGENT) < target)
        __builtin_amdgcn_s_sleep(1);
      __threadfence();   // acquire: invalidate L1/L2 so hbuf reads are fresh
    }
    __syncthreads();

    // y = h_{t-1} @ R_chunk^T   (A straight from global, B from registers)
    f32x4 acc0 = {0.f, 0.f, 0.f, 0.f}, acc1 = {0.f, 0.f, 0.f, 0.f};
    #pragma unroll
    for (int kt = 0; kt < 32; ++kt) {
      const bf16x8 a = *(const bf16x8*)&hin[abase + kt * 32];
      acc0 = mfma16(a, rb[0][kt], acc0);
      acc1 = mfma16(a, rb[1][kt], acc1);
    }

    // blend + publish
    #pragma unroll
    for (int nt = 0; nt < 2; ++nt)
      #pragma unroll
      for (int r = 0; r < 4; ++r) {
        const size_t idx = (size_t)(B0 + lhi * 4 + r) * 1024 + (cb + nt * 16 + l15);
        const float y  = (nt ? acc1[r] : acc0[r]) + wxv[nt][r];
        const float c  = tanhf(y);
        const float d  = dv[nt][r];
        const float hn = hloc[nt][r] + d * (c - hloc[nt][r]);
        hloc[nt][r] = hn;
        outp[idx] = hn;                 // overwrites wx (already consumed)
        hout[idx] = f2bf(hn);
      }
    __syncthreads();
    if (tid == 0) { __threadfence(); atomicAdd(cnt, 1u); }
    target += 8;
  }
}

// ---------------------------------------------------------------------------
extern "C" void kernel_launch(void* const* d_in, const int* in_sizes, int n_in,
                              void* d_out, int out_size, void* d_ws, size_t ws_size,
                              hipStream_t stream) {
  const float* x    = (const float*)d_in[0];
  const float* h0   = (const float*)d_in[1];
  const float* Wx   = (const float*)d_in[2];
  const float* R    = (const float*)d_in[3];
  const float* bias = (const float*)d_in[4];
  const float* Wd   = (const float*)d_in[5];
  const float* bd   = (const float*)d_in[6];
  float* out = (float*)d_out;

  // ws layout: [0,64MiB) delta bf16; [64MiB, +128KiB) hbuf (2x 32x1024 bf16);
  // counters at 64MiB+256KiB.
  unsigned short* delta_ws = (unsigned short*)d_ws;
  unsigned short* hbuf     = delta_ws + (size_t)32768 * 1024;
  unsigned int*   counters = (unsigned int*)((char*)d_ws + 64ull * 1024 * 1024 + 256 * 1024);

  hipMemsetAsync(counters, 0, 256, stream);

  dim3 pg(256, 16);
  proj_kernel<<<pg, 256, 0, stream>>>(x, Wx, Wd, bias, bd, out, delta_ws);
  rnn_kernel<<<16, 256, 0, stream>>>(R, h0, out, delta_ws, hbuf, counters);
}